// Round 3
// baseline (791.274 us; speedup 1.0000x reference)
//
#include <hip/hip_runtime.h>

// GCN layer: out = relu(x @ W_self^T + b_self + segment_mean(x[src], dst) @ W_neigh^T)
// N = 100000 nodes, D = 64, E = 1.25M edges.
//
// Pipeline: bucket hist (64-node buckets, padded counters) -> scan -> bin (src,dst)
// pairs into bucket-grouped regions -> per-bucket LDS-accumulator gather (no global
// atomics, coalesced x row reads) -> register-tiled fp32 GEMM epilogue.
// agg lives in d_out (each GEMM block reads its tile before overwriting).

#define BSH 6                 // log2(nodes per bucket)
#define BNODES 64             // nodes per bucket
#define CSTRIDE 16            // counter padding: one counter per 64B line

__global__ __launch_bounds__(256) void bucket_hist(const int* __restrict__ dst,
                                                   int* __restrict__ bcnt, int E) {
  int e = blockIdx.x * 256 + threadIdx.x;
  if (e < E) atomicAdd(&bcnt[(dst[e] >> BSH) * CSTRIDE], 1);
}

// Single block, 1024 threads, handles NB <= 2048 buckets (NB = 1563 here).
__global__ __launch_bounds__(1024) void bucket_scan(const int* __restrict__ bcnt,
                                                    int* __restrict__ bstart,
                                                    int* __restrict__ cursor,
                                                    int NB, int E) {
  __shared__ int sh[1024];
  int t = threadIdx.x;
  int i0 = 2 * t, i1 = 2 * t + 1;
  int v0 = (i0 < NB) ? bcnt[i0 * CSTRIDE] : 0;
  int v1 = (i1 < NB) ? bcnt[i1 * CSTRIDE] : 0;
  int s = v0 + v1;
  sh[t] = s;
  __syncthreads();
  for (int off = 1; off < 1024; off <<= 1) {
    int u = (t >= off) ? sh[t - off] : 0;
    __syncthreads();
    sh[t] += u;
    __syncthreads();
  }
  int ex = sh[t] - s;  // exclusive prefix of this thread's pair
  if (i0 < NB) { bstart[i0] = ex;      cursor[i0 * CSTRIDE] = ex; }
  if (i1 < NB) { bstart[i1] = ex + v0; cursor[i1 * CSTRIDE] = ex + v0; }
  if (t == 0) bstart[NB] = E;
}

__global__ __launch_bounds__(256) void bucket_bin(const int* __restrict__ src,
                                                  const int* __restrict__ dst,
                                                  int* __restrict__ cursor,
                                                  int2* __restrict__ pairs, int E) {
  int e = blockIdx.x * 256 + threadIdx.x;
  if (e < E) {
    int d = dst[e];
    int p = atomicAdd(&cursor[(d >> BSH) * CSTRIDE], 1);
    pairs[p] = make_int2(src[e], d);  // bucket-grouped -> temporally clustered lines
  }
}

// One block per bucket. acc[64 nodes x 64 dims] in LDS; wave = one edge per step,
// lane = feature dim. x row reads are coalesced 256B; ds_add_f32 is conflict-free
// (lane-consecutive, 2 lanes/bank). Mean (deg clip) folded into the write-out.
__global__ __launch_bounds__(256) void bucket_gather(const float* __restrict__ x,
                                                     const int* __restrict__ bstart,
                                                     const int2* __restrict__ pairs,
                                                     float* __restrict__ agg, int N) {
  __shared__ __align__(16) float acc[BNODES * 64];
  __shared__ int degc[BNODES];
  int tid = threadIdx.x;
  int b = blockIdx.x;

  float4* acc4 = (float4*)acc;
#pragma unroll
  for (int i = 0; i < 4; ++i) acc4[tid + 256 * i] = make_float4(0.f, 0.f, 0.f, 0.f);
  if (tid < BNODES) degc[tid] = 0;
  __syncthreads();

  int lane = tid & 63, w = tid >> 6;
  int s = bstart[b], e = bstart[b + 1];
  // waves take interleaved chunks of 2 edges -> 2 row loads in flight per wave
  for (int j = s + 2 * w; j < e; j += 8) {
    int2 p0 = pairs[j];
    bool h1 = (j + 1) < e;
    int2 p1 = h1 ? pairs[j + 1] : p0;
    float v0 = x[(long long)p0.x * 64 + lane];
    float v1 = h1 ? x[(long long)p1.x * 64 + lane] : 0.f;
    atomicAdd(&acc[(p0.y & (BNODES - 1)) * 64 + lane], v0);
    if (h1) atomicAdd(&acc[(p1.y & (BNODES - 1)) * 64 + lane], v1);
    if (lane == 0) {
      atomicAdd(&degc[p0.y & (BNODES - 1)], 1);
      if (h1) atomicAdd(&degc[p1.y & (BNODES - 1)], 1);
    }
  }
  __syncthreads();

  int base = b << BSH;
  for (int i = tid; i < BNODES * 16; i += 256) {
    int n = i >> 4, c = i & 15;
    int node = base + n;
    if (node < N) {
      float dg = (float)degc[n];
      float inv = 1.0f / (dg < 1.f ? 1.f : dg);
      float4 v = *(float4*)&acc[n * 64 + c * 4];
      v.x *= inv; v.y *= inv; v.z *= inv; v.w *= inv;
      *(float4*)&agg[(long long)node * 64 + c * 4] = v;  // coalesced 16B/lane
    }
  }
}

static __device__ inline void fma4(float4& a, float s, const float4& w) {
  a.x = fmaf(s, w.x, a.x);
  a.y = fmaf(s, w.y, a.y);
  a.z = fmaf(s, w.z, a.z);
  a.w = fmaf(s, w.w, a.w);
}

// 64-node tile per block; thread (tn,to) computes nodes 4tn..4tn+3 x outs 4to..4to+3.
// agg_out is d_out: holds agg (mean) on entry, final output on exit.
__global__ __launch_bounds__(256) void gcn_gemm(const float* __restrict__ x,
                                                float* __restrict__ agg_out,
                                                const float* __restrict__ Wself,
                                                const float* __restrict__ bself,
                                                const float* __restrict__ Wneigh,
                                                int N) {
  __shared__ __align__(16) float sWs[64 * 64];  // sWs[k*64+o] = Wself[o][k]
  __shared__ __align__(16) float sWn[64 * 64];
  __shared__ __align__(16) float xT[64 * 68];   // xT[k*68+n] = x[node][k], padded
  __shared__ __align__(16) float aT[64 * 68];
  int tid = threadIdx.x;
  int gBase = blockIdx.x * 64;

  for (int i = tid; i < 4096; i += 256) {  // stage weights transposed
    int o = i >> 6, k = i & 63;
    sWs[k * 64 + o] = Wself[i];
    sWn[k * 64 + o] = Wneigh[i];
  }
  for (int i = tid; i < 4096; i += 256) {  // stage x/agg tiles transposed
    int n = i >> 6, k = i & 63;            // per-wave: n uniform, k = lane (coalesced)
    int node = gBase + n;
    float xv = 0.f, av = 0.f;
    if (node < N) {
      xv = x[(long long)node * 64 + k];
      av = agg_out[(long long)node * 64 + k];
    }
    xT[k * 68 + n] = xv;
    aT[k * 68 + n] = av;
  }
  __syncthreads();

  int to = tid & 15, tn = tid >> 4;
  float4 acc[4];
#pragma unroll
  for (int i = 0; i < 4; ++i) acc[i] = make_float4(0.f, 0.f, 0.f, 0.f);

#pragma unroll 8
  for (int k = 0; k < 64; ++k) {
    float4 xa = *(const float4*)&xT[k * 68 + 4 * tn];
    float4 aa = *(const float4*)&aT[k * 68 + 4 * tn];
    float4 ws = *(const float4*)&sWs[k * 64 + 4 * to];
    float4 wn = *(const float4*)&sWn[k * 64 + 4 * to];
    fma4(acc[0], xa.x, ws); fma4(acc[0], aa.x, wn);
    fma4(acc[1], xa.y, ws); fma4(acc[1], aa.y, wn);
    fma4(acc[2], xa.z, ws); fma4(acc[2], aa.z, wn);
    fma4(acc[3], xa.w, ws); fma4(acc[3], aa.w, wn);
  }

  float4 bv = *(const float4*)&bself[4 * to];
#pragma unroll
  for (int i = 0; i < 4; ++i) {
    int node = gBase + 4 * tn + i;
    if (node < N) {
      float4 v = acc[i];
      v.x = fmaxf(v.x + bv.x, 0.f);
      v.y = fmaxf(v.y + bv.y, 0.f);
      v.z = fmaxf(v.z + bv.z, 0.f);
      v.w = fmaxf(v.w + bv.w, 0.f);
      *(float4*)&agg_out[(long long)node * 64 + 4 * to] = v;
    }
  }
}

extern "C" void kernel_launch(void* const* d_in, const int* in_sizes, int n_in,
                              void* d_out, int out_size, void* d_ws, size_t ws_size,
                              hipStream_t stream) {
  const float* x      = (const float*)d_in[0];
  const int*   eidx   = (const int*)d_in[1];
  const float* Wself  = (const float*)d_in[2];
  const float* bself  = (const float*)d_in[3];
  const float* Wneigh = (const float*)d_in[4];
  float* out = (float*)d_out;

  const int N = in_sizes[0] / 64;
  const int E = in_sizes[1] / 2;
  const int* src = eidx;      // edge_index row 0
  const int* dst = eidx + E;  // edge_index row 1
  const int NB = (N + BNODES - 1) / BNODES;  // 1563

  // ws layout (ints): bcnt[NB*16] | cursor[NB*16] | bstart[NB+1] | pairs[E] (int2)
  int* bcnt   = (int*)d_ws;
  int* cursor = bcnt + NB * CSTRIDE;
  int* bstart = cursor + NB * CSTRIDE;
  int2* pairs = (int2*)(bstart + NB + 1 + 1);  // +1 pad for int2 alignment

  hipMemsetAsync(bcnt, 0, (size_t)NB * CSTRIDE * sizeof(int), stream);

  int eb = (E + 255) / 256;
  bucket_hist<<<eb, 256, 0, stream>>>(dst, bcnt, E);
  bucket_scan<<<1, 1024, 0, stream>>>(bcnt, bstart, cursor, NB, E);
  bucket_bin<<<eb, 256, 0, stream>>>(src, dst, cursor, pairs, E);
  bucket_gather<<<NB, 256, 0, stream>>>(x, bstart, pairs, out, N);
  gcn_gemm<<<(N + 63) / 64, 256, 0, stream>>>(x, out, Wself, bself, Wneigh, N);
}

// Round 4
// 377.296 us; speedup vs baseline: 2.0972x; 2.0972x over previous
//
#include <hip/hip_runtime.h>

// GCN layer: out = relu(x @ W_self^T + b_self + segment_mean(x[src], dst) @ W_neigh^T)
// N = 100000 nodes, D = 64, E = 1.25M edges.
//
// Pipeline: sub-bucket hist (16-node buckets, line-padded counters) -> single-block
// scan -> bin packed (src | node_local<<17) entries bucket-grouped -> gather with
// one WAVE per sub-bucket, REGISTER accumulators (no atomics, no LDS, deep load
// ILP via uniform-switch accumulate) -> register-tiled fp32 GEMM epilogue.
// agg lives in d_out (each GEMM block reads its tile before overwriting).

#define SBSH 4                // log2(nodes per sub-bucket)
#define SBN 16                // nodes per sub-bucket
#define CSTRIDE 16            // counter padding: one counter per 64B line

__global__ __launch_bounds__(256) void sb_hist(const int* __restrict__ dst,
                                               int* __restrict__ bcnt, int E) {
  int e = blockIdx.x * 256 + threadIdx.x;
  if (e < E) atomicAdd(&bcnt[(dst[e] >> SBSH) * CSTRIDE], 1);
}

// Single block, 1024 threads, loops over NSB (=6250) in chunks with a carry.
__global__ __launch_bounds__(1024) void sb_scan(const int* __restrict__ bcnt,
                                                int* __restrict__ bstart,
                                                int* __restrict__ cursor,
                                                int NSB, int E) {
  __shared__ int sh[1024];
  __shared__ int carry;
  int t = threadIdx.x;
  if (t == 0) carry = 0;
  __syncthreads();
  for (int c = 0; c < NSB; c += 1024) {
    int i = c + t;
    int v = (i < NSB) ? bcnt[i * CSTRIDE] : 0;
    sh[t] = v;
    __syncthreads();
    for (int off = 1; off < 1024; off <<= 1) {
      int u = (t >= off) ? sh[t - off] : 0;
      __syncthreads();
      sh[t] += u;
      __syncthreads();
    }
    int excl = sh[t] - v + carry;  // carry is from previous chunk (sync'd below)
    if (i < NSB) { bstart[i] = excl; cursor[i * CSTRIDE] = excl; }
    int total = sh[1023];
    __syncthreads();
    if (t == 0) carry += total;
    __syncthreads();
  }
  if (t == 0) bstart[NSB] = E;
}

__global__ __launch_bounds__(256) void sb_bin(const int* __restrict__ src,
                                              const int* __restrict__ dst,
                                              int* __restrict__ cursor,
                                              int* __restrict__ ebuf, int E) {
  int e = blockIdx.x * 256 + threadIdx.x;
  if (e < E) {
    int d = dst[e];
    int p = atomicAdd(&cursor[(d >> SBSH) * CSTRIDE], 1);
    // consecutive claims of a sub-bucket -> consecutive addresses -> L2 merges
    ebuf[p] = src[e] | ((d & (SBN - 1)) << 17);  // src < 2^17
  }
}

// One 64-lane wave per 16-node sub-bucket. lane = feature dim. Accumulators in
// REGISTERS (a0..a15); packed entry broadcast to SGPR via readfirstlane so the
// 16-way select is uniform scalar control flow. x row reads are coalesced 256B,
// 4 independent loads per iteration, no LDS/atomics -> full pipelining.
__global__ __launch_bounds__(256) void sb_gather(const float* __restrict__ x,
                                                 const int* __restrict__ bstart,
                                                 const int* __restrict__ ebuf,
                                                 float* __restrict__ agg,
                                                 int N, int NSB) {
  int lane = threadIdx.x & 63;
  int sb = blockIdx.x * 4 + (threadIdx.x >> 6);
  if (sb >= NSB) return;
  int s = bstart[sb], e = bstart[sb + 1];

  float a0 = 0.f, a1 = 0.f, a2 = 0.f, a3 = 0.f, a4 = 0.f, a5 = 0.f, a6 = 0.f, a7 = 0.f;
  float a8 = 0.f, a9 = 0.f, a10 = 0.f, a11 = 0.f, a12 = 0.f, a13 = 0.f, a14 = 0.f, a15 = 0.f;
  float dg = 0.f;

#define ACC_ADD(NL, V)                                           \
  do {                                                           \
    dg += (lane == (NL)) ? 1.0f : 0.0f;                          \
    switch (NL) {                                                \
      case 0: a0 += (V); break;   case 1: a1 += (V); break;      \
      case 2: a2 += (V); break;   case 3: a3 += (V); break;      \
      case 4: a4 += (V); break;   case 5: a5 += (V); break;      \
      case 6: a6 += (V); break;   case 7: a7 += (V); break;      \
      case 8: a8 += (V); break;   case 9: a9 += (V); break;      \
      case 10: a10 += (V); break; case 11: a11 += (V); break;    \
      case 12: a12 += (V); break; case 13: a13 += (V); break;    \
      case 14: a14 += (V); break; default: a15 += (V); break;    \
    }                                                            \
  } while (0)

  int j = s;
  for (; j + 4 <= e; j += 4) {
    int p0 = __builtin_amdgcn_readfirstlane(ebuf[j]);
    int p1 = __builtin_amdgcn_readfirstlane(ebuf[j + 1]);
    int p2 = __builtin_amdgcn_readfirstlane(ebuf[j + 2]);
    int p3 = __builtin_amdgcn_readfirstlane(ebuf[j + 3]);
    // 4 independent coalesced 256B row loads in flight
    float v0 = x[(long long)(p0 & 0x1FFFF) * 64 + lane];
    float v1 = x[(long long)(p1 & 0x1FFFF) * 64 + lane];
    float v2 = x[(long long)(p2 & 0x1FFFF) * 64 + lane];
    float v3 = x[(long long)(p3 & 0x1FFFF) * 64 + lane];
    ACC_ADD(p0 >> 17, v0);
    ACC_ADD(p1 >> 17, v1);
    ACC_ADD(p2 >> 17, v2);
    ACC_ADD(p3 >> 17, v3);
  }
  for (; j < e; ++j) {
    int p = __builtin_amdgcn_readfirstlane(ebuf[j]);
    float v = x[(long long)(p & 0x1FFFF) * 64 + lane];
    ACC_ADD(p >> 17, v);
  }

  int base = sb << SBSH;
#define OUT_ROW(NL, AN)                                          \
  do {                                                           \
    int node = base + (NL);                                      \
    if (node < N) {                                              \
      float c = __shfl(dg, (NL), 64);                            \
      float inv = 1.0f / fmaxf(c, 1.0f);                         \
      agg[(long long)node * 64 + lane] = (AN) * inv;             \
    }                                                            \
  } while (0)
  OUT_ROW(0, a0);   OUT_ROW(1, a1);   OUT_ROW(2, a2);   OUT_ROW(3, a3);
  OUT_ROW(4, a4);   OUT_ROW(5, a5);   OUT_ROW(6, a6);   OUT_ROW(7, a7);
  OUT_ROW(8, a8);   OUT_ROW(9, a9);   OUT_ROW(10, a10); OUT_ROW(11, a11);
  OUT_ROW(12, a12); OUT_ROW(13, a13); OUT_ROW(14, a14); OUT_ROW(15, a15);
}

static __device__ inline void fma4(float4& a, float s, const float4& w) {
  a.x = fmaf(s, w.x, a.x);
  a.y = fmaf(s, w.y, a.y);
  a.z = fmaf(s, w.z, a.z);
  a.w = fmaf(s, w.w, a.w);
}

// 64-node tile per block; thread (tn,to) computes nodes 4tn..4tn+3 x outs 4to..4to+3.
// agg_out is d_out: holds agg (mean) on entry, final output on exit.
__global__ __launch_bounds__(256) void gcn_gemm(const float* __restrict__ x,
                                                float* __restrict__ agg_out,
                                                const float* __restrict__ Wself,
                                                const float* __restrict__ bself,
                                                const float* __restrict__ Wneigh,
                                                int N) {
  __shared__ __align__(16) float sWs[64 * 64];  // sWs[k*64+o] = Wself[o][k]
  __shared__ __align__(16) float sWn[64 * 64];
  __shared__ __align__(16) float xT[64 * 68];   // xT[k*68+n] = x[node][k], padded
  __shared__ __align__(16) float aT[64 * 68];
  int tid = threadIdx.x;
  int gBase = blockIdx.x * 64;

  for (int i = tid; i < 4096; i += 256) {  // stage weights transposed
    int o = i >> 6, k = i & 63;
    sWs[k * 64 + o] = Wself[i];
    sWn[k * 64 + o] = Wneigh[i];
  }
  for (int i = tid; i < 4096; i += 256) {  // stage x/agg tiles transposed
    int n = i >> 6, k = i & 63;            // per-wave: n uniform, k = lane (coalesced)
    int node = gBase + n;
    float xv = 0.f, av = 0.f;
    if (node < N) {
      xv = x[(long long)node * 64 + k];
      av = agg_out[(long long)node * 64 + k];
    }
    xT[k * 68 + n] = xv;
    aT[k * 68 + n] = av;
  }
  __syncthreads();

  int to = tid & 15, tn = tid >> 4;
  float4 acc[4];
#pragma unroll
  for (int i = 0; i < 4; ++i) acc[i] = make_float4(0.f, 0.f, 0.f, 0.f);

#pragma unroll 8
  for (int k = 0; k < 64; ++k) {
    float4 xa = *(const float4*)&xT[k * 68 + 4 * tn];
    float4 aa = *(const float4*)&aT[k * 68 + 4 * tn];
    float4 ws = *(const float4*)&sWs[k * 64 + 4 * to];
    float4 wn = *(const float4*)&sWn[k * 64 + 4 * to];
    fma4(acc[0], xa.x, ws); fma4(acc[0], aa.x, wn);
    fma4(acc[1], xa.y, ws); fma4(acc[1], aa.y, wn);
    fma4(acc[2], xa.z, ws); fma4(acc[2], aa.z, wn);
    fma4(acc[3], xa.w, ws); fma4(acc[3], aa.w, wn);
  }

  float4 bv = *(const float4*)&bself[4 * to];
#pragma unroll
  for (int i = 0; i < 4; ++i) {
    int node = gBase + 4 * tn + i;
    if (node < N) {
      float4 v = acc[i];
      v.x = fmaxf(v.x + bv.x, 0.f);
      v.y = fmaxf(v.y + bv.y, 0.f);
      v.z = fmaxf(v.z + bv.z, 0.f);
      v.w = fmaxf(v.w + bv.w, 0.f);
      *(float4*)&agg_out[(long long)node * 64 + 4 * to] = v;
    }
  }
}

extern "C" void kernel_launch(void* const* d_in, const int* in_sizes, int n_in,
                              void* d_out, int out_size, void* d_ws, size_t ws_size,
                              hipStream_t stream) {
  const float* x      = (const float*)d_in[0];
  const int*   eidx   = (const int*)d_in[1];
  const float* Wself  = (const float*)d_in[2];
  const float* bself  = (const float*)d_in[3];
  const float* Wneigh = (const float*)d_in[4];
  float* out = (float*)d_out;

  const int N = in_sizes[0] / 64;
  const int E = in_sizes[1] / 2;
  const int* src = eidx;      // edge_index row 0
  const int* dst = eidx + E;  // edge_index row 1
  const int NSB = (N + SBN - 1) / SBN;  // 6250 sub-buckets of 16 nodes

  // ws layout (ints): bcnt[NSB*16] | cursor[NSB*16] | bstart[NSB+1] | ebuf[E]
  int* bcnt   = (int*)d_ws;
  int* cursor = bcnt + NSB * CSTRIDE;
  int* bstart = cursor + NSB * CSTRIDE;
  int* ebuf   = bstart + NSB + 1;

  hipMemsetAsync(bcnt, 0, (size_t)NSB * CSTRIDE * sizeof(int), stream);

  int eb = (E + 255) / 256;
  sb_hist<<<eb, 256, 0, stream>>>(dst, bcnt, E);
  sb_scan<<<1, 1024, 0, stream>>>(bcnt, bstart, cursor, NSB, E);
  sb_bin<<<eb, 256, 0, stream>>>(src, dst, cursor, ebuf, E);
  sb_gather<<<(NSB + 3) / 4, 256, 0, stream>>>(x, bstart, ebuf, out, N, NSB);
  gcn_gemm<<<(N + 63) / 64, 256, 0, stream>>>(x, out, Wself, bself, Wneigh, N);
}

// Round 5
// 359.741 us; speedup vs baseline: 2.1996x; 1.0488x over previous
//
#include <hip/hip_runtime.h>

// GCN layer: out = relu(x @ W_self^T + b_self + segment_mean(x[src], dst) @ W_neigh^T)
// N = 100000 nodes, D = 64, E = 1.25M edges.
//
// Pipeline:
//   sb_hist  : coarse 16-node-bucket histogram (line-padded counters)
//   sb_scan  : single-block wave-shfl exclusive scan -> bucket starts
//   sb_bin   : scatter packed (src | node_local<<17) entries, bucket-grouped
//              (consecutive claims -> consecutive addresses -> L2 merges lines)
//   sb_csr   : per-bucket LDS int-histogram + local node-sort within the bucket's
//              contiguous window -> exact CSR (rowptr + node-sorted src list)
//   gather   : one wave per node, plain register adds (1 v_add/edge), 4-deep ILP
//   gemm     : register-tiled fp32 epilogue, bias+relu fused
// agg lives in d_out (each GEMM block reads its tile before overwriting).

#define SBSH 4                // log2(nodes per coarse bucket)
#define SBN 16                // nodes per coarse bucket
#define CSTRIDE 16            // counter padding: one counter per 64B line

__global__ __launch_bounds__(256) void sb_hist(const int* __restrict__ dst,
                                               int* __restrict__ bcnt, int E) {
  int e = blockIdx.x * 256 + threadIdx.x;
  if (e < E) atomicAdd(&bcnt[(dst[e] >> SBSH) * CSTRIDE], 1);
}

// Single block, 1024 threads x 8 items = 8192 >= NSB (6250). Two barriers total.
__global__ __launch_bounds__(1024) void sb_scan(const int* __restrict__ bcnt,
                                                int* __restrict__ bstart,
                                                int* __restrict__ cursor,
                                                int NSB, int E) {
  __shared__ int wsum[16];
  int t = threadIdx.x;
  int lane = t & 63, w = t >> 6;
  int v[8];
  int tot = 0;
#pragma unroll
  for (int i = 0; i < 8; ++i) {
    int idx = t * 8 + i;
    v[i] = (idx < NSB) ? bcnt[idx * CSTRIDE] : 0;
    tot += v[i];
  }
  int inc = tot;  // wave inclusive scan of per-thread totals
#pragma unroll
  for (int off = 1; off < 64; off <<= 1) {
    int u = __shfl_up(inc, off, 64);
    if (lane >= off) inc += u;
  }
  if (lane == 63) wsum[w] = inc;
  __syncthreads();
  if (t < 16) {  // scan the 16 wave sums in wave 0
    int s = wsum[t];
    int incw = s;
#pragma unroll
    for (int off = 1; off < 16; off <<= 1) {
      int u = __shfl_up(incw, off, 64);
      if (lane >= off) incw += u;
    }
    wsum[t] = incw - s;  // exclusive
  }
  __syncthreads();
  int ex = wsum[w] + (inc - tot);
#pragma unroll
  for (int i = 0; i < 8; ++i) {
    int idx = t * 8 + i;
    if (idx < NSB) { bstart[idx] = ex; cursor[idx * CSTRIDE] = ex; }
    ex += v[i];
  }
  if (t == 0) bstart[NSB] = E;
}

__global__ __launch_bounds__(256) void sb_bin(const int* __restrict__ src,
                                              const int* __restrict__ dst,
                                              int* __restrict__ cursor,
                                              int* __restrict__ ebuf, int E) {
  int e = blockIdx.x * 256 + threadIdx.x;
  if (e < E) {
    int d = dst[e];
    int p = atomicAdd(&cursor[(d >> SBSH) * CSTRIDE], 1);
    ebuf[p] = src[e] | ((d & (SBN - 1)) << 17);  // src < 2^17
  }
}

// One block per coarse bucket: node-sort the bucket's entries in its own
// contiguous window (writes hit ~13 hot L2 lines), emit exact rowptr.
// LDS int atomics are native ds_add (fast), unlike fp32 CAS.
__global__ __launch_bounds__(256) void sb_csr(const int* __restrict__ bstart,
                                              const int* __restrict__ ebuf,
                                              int* __restrict__ col,
                                              int* __restrict__ rowptr,
                                              int N, int E) {
  __shared__ int cnt[SBN];
  __shared__ int off[SBN];
  int b = blockIdx.x;
  int t = threadIdx.x;
  int s = bstart[b], e = bstart[b + 1];
  if (t < SBN) cnt[t] = 0;
  __syncthreads();
  for (int j = s + t; j < e; j += 256)
    atomicAdd(&cnt[(ebuf[j] >> 17) & (SBN - 1)], 1);
  __syncthreads();
  if (t == 0) {
    int acc = 0;
#pragma unroll
    for (int i = 0; i < SBN; ++i) { off[i] = acc; acc += cnt[i]; }
  }
  __syncthreads();
  if (t < SBN) {
    int node = (b << SBSH) + t;
    if (node < N) rowptr[node] = s + off[t];
    cnt[t] = 0;  // reuse as cursor
  }
  __syncthreads();
  for (int j = s + t; j < e; j += 256) {
    int v = ebuf[j];
    int nl = (v >> 17) & (SBN - 1);
    int p = atomicAdd(&cnt[nl], 1);
    col[s + off[nl] + p] = v & 0x1FFFF;  // src only, node-sorted
  }
  if (b == 0 && t == 0) rowptr[N] = E;
}

// One 64-lane wave per node: lane = feature dim, plain register adds (1 v_add
// per edge), coalesced 256B row reads, 4 independent loads in flight.
__global__ __launch_bounds__(256) void gcn_gather(const float* __restrict__ x,
                                                  const int* __restrict__ rowptr,
                                                  const int* __restrict__ col,
                                                  float* __restrict__ agg, int N) {
  int gid = blockIdx.x * 256 + threadIdx.x;
  int node = gid >> 6, lane = gid & 63;
  if (node >= N) return;
  int s = rowptr[node], e = rowptr[node + 1];
  float a0 = 0.f, a1 = 0.f, a2 = 0.f, a3 = 0.f;
  int j = s;
  for (; j + 4 <= e; j += 4) {
    int c0 = col[j], c1 = col[j + 1], c2 = col[j + 2], c3 = col[j + 3];
    a0 += x[(long long)c0 * 64 + lane];
    a1 += x[(long long)c1 * 64 + lane];
    a2 += x[(long long)c2 * 64 + lane];
    a3 += x[(long long)c3 * 64 + lane];
  }
  for (; j < e; ++j) a0 += x[(long long)col[j] * 64 + lane];
  float cnt = (float)(e - s);
  float inv = 1.0f / fmaxf(cnt, 1.0f);
  agg[(long long)node * 64 + lane] = (a0 + a1 + a2 + a3) * inv;
}

static __device__ inline void fma4(float4& a, float s, const float4& w) {
  a.x = fmaf(s, w.x, a.x);
  a.y = fmaf(s, w.y, a.y);
  a.z = fmaf(s, w.z, a.z);
  a.w = fmaf(s, w.w, a.w);
}

// 64-node tile per block; thread (tn,to) computes nodes 4tn..4tn+3 x outs 4to..4to+3.
// agg_out is d_out: holds agg (mean) on entry, final output on exit.
__global__ __launch_bounds__(256) void gcn_gemm(const float* __restrict__ x,
                                                float* __restrict__ agg_out,
                                                const float* __restrict__ Wself,
                                                const float* __restrict__ bself,
                                                const float* __restrict__ Wneigh,
                                                int N) {
  __shared__ __align__(16) float sWs[64 * 64];  // sWs[k*64+o] = Wself[o][k]
  __shared__ __align__(16) float sWn[64 * 64];
  __shared__ __align__(16) float xT[64 * 68];   // xT[k*68+n] = x[node][k], padded
  __shared__ __align__(16) float aT[64 * 68];
  int tid = threadIdx.x;
  int gBase = blockIdx.x * 64;

  for (int i = tid; i < 4096; i += 256) {
    int o = i >> 6, k = i & 63;
    sWs[k * 64 + o] = Wself[i];
    sWn[k * 64 + o] = Wneigh[i];
  }
  for (int i = tid; i < 4096; i += 256) {
    int n = i >> 6, k = i & 63;
    int node = gBase + n;
    float xv = 0.f, av = 0.f;
    if (node < N) {
      xv = x[(long long)node * 64 + k];
      av = agg_out[(long long)node * 64 + k];
    }
    xT[k * 68 + n] = xv;
    aT[k * 68 + n] = av;
  }
  __syncthreads();

  int to = tid & 15, tn = tid >> 4;
  float4 acc[4];
#pragma unroll
  for (int i = 0; i < 4; ++i) acc[i] = make_float4(0.f, 0.f, 0.f, 0.f);

#pragma unroll 8
  for (int k = 0; k < 64; ++k) {
    float4 xa = *(const float4*)&xT[k * 68 + 4 * tn];
    float4 aa = *(const float4*)&aT[k * 68 + 4 * tn];
    float4 ws = *(const float4*)&sWs[k * 64 + 4 * to];
    float4 wn = *(const float4*)&sWn[k * 64 + 4 * to];
    fma4(acc[0], xa.x, ws); fma4(acc[0], aa.x, wn);
    fma4(acc[1], xa.y, ws); fma4(acc[1], aa.y, wn);
    fma4(acc[2], xa.z, ws); fma4(acc[2], aa.z, wn);
    fma4(acc[3], xa.w, ws); fma4(acc[3], aa.w, wn);
  }

  float4 bv = *(const float4*)&bself[4 * to];
#pragma unroll
  for (int i = 0; i < 4; ++i) {
    int node = gBase + 4 * tn + i;
    if (node < N) {
      float4 v = acc[i];
      v.x = fmaxf(v.x + bv.x, 0.f);
      v.y = fmaxf(v.y + bv.y, 0.f);
      v.z = fmaxf(v.z + bv.z, 0.f);
      v.w = fmaxf(v.w + bv.w, 0.f);
      *(float4*)&agg_out[(long long)node * 64 + 4 * to] = v;
    }
  }
}

extern "C" void kernel_launch(void* const* d_in, const int* in_sizes, int n_in,
                              void* d_out, int out_size, void* d_ws, size_t ws_size,
                              hipStream_t stream) {
  const float* x      = (const float*)d_in[0];
  const int*   eidx   = (const int*)d_in[1];
  const float* Wself  = (const float*)d_in[2];
  const float* bself  = (const float*)d_in[3];
  const float* Wneigh = (const float*)d_in[4];
  float* out = (float*)d_out;

  const int N = in_sizes[0] / 64;
  const int E = in_sizes[1] / 2;
  const int* src = eidx;      // edge_index row 0
  const int* dst = eidx + E;  // edge_index row 1
  const int NSB = (N + SBN - 1) / SBN;  // 6250 coarse buckets

  // ws layout (ints): bcnt[NSB*16] | cursor[NSB*16] | bstart[NSB+1] | rowptr[N+1]
  //                   | ebuf[E] | col[E]
  int* bcnt   = (int*)d_ws;
  int* cursor = bcnt + NSB * CSTRIDE;
  int* bstart = cursor + NSB * CSTRIDE;
  int* rowptr = bstart + NSB + 1;
  int* ebuf   = rowptr + N + 1;
  int* col    = ebuf + E;

  hipMemsetAsync(bcnt, 0, (size_t)NSB * CSTRIDE * sizeof(int), stream);

  int eb = (E + 255) / 256;
  sb_hist<<<eb, 256, 0, stream>>>(dst, bcnt, E);
  sb_scan<<<1, 1024, 0, stream>>>(bcnt, bstart, cursor, NSB, E);
  sb_bin<<<eb, 256, 0, stream>>>(src, dst, cursor, ebuf, E);
  sb_csr<<<NSB, 256, 0, stream>>>(bstart, ebuf, col, rowptr, N, E);
  gcn_gather<<<(N * 64 + 255) / 256, 256, 0, stream>>>(x, rowptr, col, out, N);
  gcn_gemm<<<(N + 63) / 64, 256, 0, stream>>>(x, out, Wself, bself, Wneigh, N);
}

// Round 6
// 263.570 us; speedup vs baseline: 3.0021x; 1.3649x over previous
//
#include <hip/hip_runtime.h>

// GCN layer: out = relu(x @ W_self^T + b_self + segment_mean(x[src], dst) @ W_neigh^T)
// N = 100000 nodes, D = 64, E = 1.25M edges.
//
// Pipeline:
//   bin_hist    : per-block LDS hist of 4096-edge chunk -> 1 global atomic per
//                 (block,bucket). Buckets = 1024 consecutive dst nodes (NB=98).
//   bin_scan    : one-wave exclusive scan of the 98 bucket counts.
//   bin_scatter : LDS-staged radix scatter — block sorts its chunk by bucket in
//                 LDS, claims a contiguous global run per bucket, streams runs out.
//                 Every ebuf line is written by ONE block -> full-line L2 merging
//                 (fixes the 66 MB cross-XCD partial-line write-through of r5).
//   sb_csr      : one block per 1024-node bucket: LDS hist + scan + local node-
//                 sort within the block-private window -> exact CSR.
//   gcn_gather  : one wave per node, register adds, 4-deep load ILP, mean folded.
//   gcn_gemm    : register-tiled fp32 epilogue, bias+relu fused.
// agg lives in d_out (each GEMM block reads its tile before overwriting).

#define BKSH 10               // log2(nodes per bucket)
#define BKN 1024              // nodes per bucket
#define CHUNK 4096            // edges per binning block
#define MAXNB 128             // >= NB = ceil(N / BKN) = 98

__global__ __launch_bounds__(256) void bin_hist(const int* __restrict__ dst,
                                                int* __restrict__ gcnt, int E, int NB) {
  __shared__ int h[MAXNB];
  int t = threadIdx.x;
  if (t < MAXNB) h[t] = 0;
  __syncthreads();
  int base = blockIdx.x * CHUNK;
#pragma unroll 4
  for (int i = t; i < CHUNK; i += 256) {
    int e = base + i;
    if (e < E) atomicAdd(&h[dst[e] >> BKSH], 1);
  }
  __syncthreads();
  if (t < NB && h[t]) atomicAdd(&gcnt[t], h[t]);
}

// One wave; thread handles 2 buckets. NB <= 128.
__global__ __launch_bounds__(64) void bin_scan(const int* __restrict__ gcnt,
                                               int* __restrict__ bstart,
                                               int* __restrict__ cursor, int NB, int E) {
  int t = threadIdx.x;
  int i0 = 2 * t, i1 = 2 * t + 1;
  int v0 = (i0 < NB) ? gcnt[i0] : 0;
  int v1 = (i1 < NB) ? gcnt[i1] : 0;
  int s = v0 + v1, inc = s;
#pragma unroll
  for (int off = 1; off < 64; off <<= 1) {
    int u = __shfl_up(inc, off, 64);
    if (t >= off) inc += u;
  }
  int ex = inc - s;
  if (i0 < NB) { bstart[i0] = ex;      cursor[i0] = ex; }
  if (i1 < NB) { bstart[i1] = ex + v0; cursor[i1] = ex + v0; }
  if (t == 0) bstart[NB] = E;
}

__global__ __launch_bounds__(256) void bin_scatter(const int* __restrict__ src,
                                                   const int* __restrict__ dst,
                                                   int* __restrict__ cursor,
                                                   int* __restrict__ ebuf, int E, int NB) {
  __shared__ int h[MAXNB], loff[MAXNB], gbase[MAXNB];
  __shared__ int sbuf[CHUNK];
  int t = threadIdx.x;
  if (t < MAXNB) h[t] = 0;
  __syncthreads();

  int base = blockIdx.x * CHUNK;
  int myd[CHUNK / 256], mys[CHUNK / 256];
#pragma unroll
  for (int i = 0; i < CHUNK / 256; ++i) {
    int e = base + t + 256 * i;  // coalesced
    if (e < E) {
      myd[i] = dst[e];
      mys[i] = src[e];
      atomicAdd(&h[myd[i] >> BKSH], 1);
    } else myd[i] = -1;
  }
  __syncthreads();

  if (t < 64) {  // wave 0: exclusive scan of h[0..127]
    int i0 = 2 * t, i1 = 2 * t + 1;
    int v0 = h[i0], v1 = h[i1];
    int s = v0 + v1, inc = s;
#pragma unroll
    for (int off = 1; off < 64; off <<= 1) {
      int u = __shfl_up(inc, off, 64);
      if (t >= off) inc += u;
    }
    int ex = inc - s;
    loff[i0] = ex; loff[i1] = ex + v0;
  }
  __syncthreads();

  if (t < NB) {
    if (h[t] > 0) gbase[t] = atomicAdd(&cursor[t], h[t]);  // claim contiguous run
  }
  if (t < MAXNB) h[t] = 0;  // reuse as local cursor (own slot only; sync below)
  __syncthreads();

#pragma unroll
  for (int i = 0; i < CHUNK / 256; ++i) {
    if (myd[i] >= 0) {
      int b = myd[i] >> BKSH;
      int p = atomicAdd(&h[b], 1);
      sbuf[loff[b] + p] = mys[i] | ((myd[i] & (BKN - 1)) << 17);  // src < 2^17
    }
  }
  __syncthreads();

  // stream each (block,bucket) run out contiguously; wave w takes buckets w,w+4,...
  int w = t >> 6, lane = t & 63;
  for (int b = w; b < NB; b += 4) {
    int c = h[b], lo = loff[b], go = gbase[b];
    for (int j = lane; j < c; j += 64)
      ebuf[go + j] = sbuf[lo + j];
  }
}

// One block per 1024-node bucket: node-sort within the block-private window.
__global__ __launch_bounds__(256) void sb_csr(const int* __restrict__ bstart,
                                              const int* __restrict__ ebuf,
                                              int* __restrict__ col,
                                              int* __restrict__ rowptr,
                                              int N, int E) {
  __shared__ int cnt[BKN], off[BKN];
  __shared__ int wsum[4];
  int b = blockIdx.x, t = threadIdx.x;
  int s = bstart[b], e = bstart[b + 1];
  for (int i = t; i < BKN; i += 256) cnt[i] = 0;
  __syncthreads();
  for (int j = s + t; j < e; j += 256)
    atomicAdd(&cnt[(ebuf[j] >> 17) & (BKN - 1)], 1);
  __syncthreads();

  // block exclusive scan over 1024 (4 per thread)
  int i0 = t * 4;
  int v0 = cnt[i0], v1 = cnt[i0 + 1], v2 = cnt[i0 + 2], v3 = cnt[i0 + 3];
  int tot = v0 + v1 + v2 + v3;
  int lane = t & 63, w = t >> 6;
  int inc = tot;
#pragma unroll
  for (int o = 1; o < 64; o <<= 1) {
    int u = __shfl_up(inc, o, 64);
    if (lane >= o) inc += u;
  }
  if (lane == 63) wsum[w] = inc;
  __syncthreads();
  int wex = 0;
  for (int i = 0; i < w; ++i) wex += wsum[i];
  int ex = wex + inc - tot;
  off[i0] = ex; off[i0 + 1] = ex + v0; off[i0 + 2] = ex + v0 + v1; off[i0 + 3] = ex + v0 + v1 + v2;
  __syncthreads();

  int nbase = b << BKSH;
  for (int i = t; i < BKN; i += 256) {
    int node = nbase + i;
    if (node < N) rowptr[node] = s + off[i];
    cnt[i] = 0;  // reuse as cursor
  }
  __syncthreads();
  for (int j = s + t; j < e; j += 256) {
    int v = ebuf[j];
    int nl = (v >> 17) & (BKN - 1);
    int p = atomicAdd(&cnt[nl], 1);
    col[s + off[nl] + p] = v & 0x1FFFF;  // node-sorted src, block-private lines
  }
  if (b == 0 && t == 0) rowptr[N] = E;
}

// One 64-lane wave per node: lane = feature dim, 1 v_add per edge, 4-deep ILP.
__global__ __launch_bounds__(256) void gcn_gather(const float* __restrict__ x,
                                                  const int* __restrict__ rowptr,
                                                  const int* __restrict__ col,
                                                  float* __restrict__ agg, int N) {
  int gid = blockIdx.x * 256 + threadIdx.x;
  int node = gid >> 6, lane = gid & 63;
  if (node >= N) return;
  int s = rowptr[node], e = rowptr[node + 1];
  float a0 = 0.f, a1 = 0.f, a2 = 0.f, a3 = 0.f;
  int j = s;
  for (; j + 4 <= e; j += 4) {
    int c0 = col[j], c1 = col[j + 1], c2 = col[j + 2], c3 = col[j + 3];
    a0 += x[(long long)c0 * 64 + lane];
    a1 += x[(long long)c1 * 64 + lane];
    a2 += x[(long long)c2 * 64 + lane];
    a3 += x[(long long)c3 * 64 + lane];
  }
  for (; j < e; ++j) a0 += x[(long long)col[j] * 64 + lane];
  float cnt = (float)(e - s);
  float inv = 1.0f / fmaxf(cnt, 1.0f);
  agg[(long long)node * 64 + lane] = (a0 + a1 + a2 + a3) * inv;
}

static __device__ inline void fma4(float4& a, float s, const float4& w) {
  a.x = fmaf(s, w.x, a.x);
  a.y = fmaf(s, w.y, a.y);
  a.z = fmaf(s, w.z, a.z);
  a.w = fmaf(s, w.w, a.w);
}

// 64-node tile per block; thread (tn,to) computes nodes 4tn..4tn+3 x outs 4to..4to+3.
// agg_out is d_out: holds agg (mean) on entry, final output on exit.
__global__ __launch_bounds__(256) void gcn_gemm(const float* __restrict__ x,
                                                float* __restrict__ agg_out,
                                                const float* __restrict__ Wself,
                                                const float* __restrict__ bself,
                                                const float* __restrict__ Wneigh,
                                                int N) {
  __shared__ __align__(16) float sWs[64 * 64];  // sWs[k*64+o] = Wself[o][k]
  __shared__ __align__(16) float sWn[64 * 64];
  __shared__ __align__(16) float xT[64 * 68];   // xT[k*68+n] = x[node][k], padded
  __shared__ __align__(16) float aT[64 * 68];
  int tid = threadIdx.x;
  int gBase = blockIdx.x * 64;

  for (int i = tid; i < 4096; i += 256) {
    int o = i >> 6, k = i & 63;
    sWs[k * 64 + o] = Wself[i];
    sWn[k * 64 + o] = Wneigh[i];
  }
  for (int i = tid; i < 4096; i += 256) {
    int n = i >> 6, k = i & 63;
    int node = gBase + n;
    float xv = 0.f, av = 0.f;
    if (node < N) {
      xv = x[(long long)node * 64 + k];
      av = agg_out[(long long)node * 64 + k];
    }
    xT[k * 68 + n] = xv;
    aT[k * 68 + n] = av;
  }
  __syncthreads();

  int to = tid & 15, tn = tid >> 4;
  float4 acc[4];
#pragma unroll
  for (int i = 0; i < 4; ++i) acc[i] = make_float4(0.f, 0.f, 0.f, 0.f);

#pragma unroll 8
  for (int k = 0; k < 64; ++k) {
    float4 xa = *(const float4*)&xT[k * 68 + 4 * tn];
    float4 aa = *(const float4*)&aT[k * 68 + 4 * tn];
    float4 ws = *(const float4*)&sWs[k * 64 + 4 * to];
    float4 wn = *(const float4*)&sWn[k * 64 + 4 * to];
    fma4(acc[0], xa.x, ws); fma4(acc[0], aa.x, wn);
    fma4(acc[1], xa.y, ws); fma4(acc[1], aa.y, wn);
    fma4(acc[2], xa.z, ws); fma4(acc[2], aa.z, wn);
    fma4(acc[3], xa.w, ws); fma4(acc[3], aa.w, wn);
  }

  float4 bv = *(const float4*)&bself[4 * to];
#pragma unroll
  for (int i = 0; i < 4; ++i) {
    int node = gBase + 4 * tn + i;
    if (node < N) {
      float4 v = acc[i];
      v.x = fmaxf(v.x + bv.x, 0.f);
      v.y = fmaxf(v.y + bv.y, 0.f);
      v.z = fmaxf(v.z + bv.z, 0.f);
      v.w = fmaxf(v.w + bv.w, 0.f);
      *(float4*)&agg_out[(long long)node * 64 + 4 * to] = v;
    }
  }
}

extern "C" void kernel_launch(void* const* d_in, const int* in_sizes, int n_in,
                              void* d_out, int out_size, void* d_ws, size_t ws_size,
                              hipStream_t stream) {
  const float* x      = (const float*)d_in[0];
  const int*   eidx   = (const int*)d_in[1];
  const float* Wself  = (const float*)d_in[2];
  const float* bself  = (const float*)d_in[3];
  const float* Wneigh = (const float*)d_in[4];
  float* out = (float*)d_out;

  const int N = in_sizes[0] / 64;
  const int E = in_sizes[1] / 2;
  const int* src = eidx;      // edge_index row 0
  const int* dst = eidx + E;  // edge_index row 1
  const int NB = (N + BKN - 1) / BKN;  // 98 buckets of 1024 nodes

  // ws layout (ints): gcnt[128] | cursor[128] | bstart[NB+1 -> 128] | rowptr[N+1]
  //                   | ebuf[E] | col[E]
  int* gcnt   = (int*)d_ws;
  int* cursor = gcnt + MAXNB;
  int* bstart = cursor + MAXNB;
  int* rowptr = bstart + MAXNB;
  int* ebuf   = rowptr + N + 1;
  int* col    = ebuf + E;

  hipMemsetAsync(gcnt, 0, MAXNB * sizeof(int), stream);

  int cb = (E + CHUNK - 1) / CHUNK;  // 306 binning blocks
  bin_hist<<<cb, 256, 0, stream>>>(dst, gcnt, E, NB);
  bin_scan<<<1, 64, 0, stream>>>(gcnt, bstart, cursor, NB, E);
  bin_scatter<<<cb, 256, 0, stream>>>(src, dst, cursor, ebuf, E, NB);
  sb_csr<<<NB, 256, 0, stream>>>(bstart, ebuf, col, rowptr, N, E);
  gcn_gather<<<(N * 64 + 255) / 256, 256, 0, stream>>>(x, rowptr, col, out, N);
  gcn_gemm<<<(N + 63) / 64, 256, 0, stream>>>(x, out, Wself, bself, Wneigh, N);
}

// Round 7
// 242.102 us; speedup vs baseline: 3.2684x; 1.0887x over previous
//
#include <hip/hip_runtime.h>

// GCN layer: out = relu(x @ W_self^T + b_self + segment_mean(x[src], dst) @ W_neigh^T)
// N = 100000 nodes, D = 64, E = 1.25M edges.
//
// Pipeline:
//   bin_hist    : per-block LDS hist of 4096-edge chunk (int4 loads) -> 1 global
//                 atomic per (block,bucket). Buckets = 1024 consecutive dst nodes.
//   bin_scan    : one-wave exclusive scan of the 98 bucket counts.
//   bin_scatter : LDS-staged radix scatter; every ebuf line written by ONE block.
//   sb_csr      : one block per 1024-node bucket -> exact CSR, block-private lines.
//   gcn_gather  : one wave per node, 16 lanes x float4 per row -> 4 edges per VMEM
//                 instruction (1KB), 2-deep unroll, shuffle cross-quarter reduce.
//   gcn_gemm    : register-tiled fp32 epilogue, stride-65 LDS (conflict-free).
// agg lives in d_out (each GEMM block reads its tile before overwriting).

#define BKSH 10               // log2(nodes per bucket)
#define BKN 1024              // nodes per bucket
#define CHUNK 4096            // edges per binning block
#define MAXNB 128             // >= NB = ceil(N / BKN) = 98
#define LP 65                 // LDS row stride (pad 64+1): bank = (lane+c)%32

__global__ __launch_bounds__(256) void bin_hist(const int* __restrict__ dst,
                                                int* __restrict__ gcnt, int E, int NB) {
  __shared__ int h[MAXNB];
  int t = threadIdx.x;
  if (t < MAXNB) h[t] = 0;
  __syncthreads();
  int base = blockIdx.x * CHUNK;
  if (base + CHUNK <= E) {  // full chunk: int4 loads
    const int4* d4 = (const int4*)(dst + base);
#pragma unroll
    for (int i = 0; i < 4; ++i) {
      int4 v = d4[t + 256 * i];
      atomicAdd(&h[v.x >> BKSH], 1);
      atomicAdd(&h[v.y >> BKSH], 1);
      atomicAdd(&h[v.z >> BKSH], 1);
      atomicAdd(&h[v.w >> BKSH], 1);
    }
  } else {
    for (int i = t; i < CHUNK; i += 256) {
      int e = base + i;
      if (e < E) atomicAdd(&h[dst[e] >> BKSH], 1);
    }
  }
  __syncthreads();
  if (t < NB && h[t]) atomicAdd(&gcnt[t], h[t]);
}

// One wave; thread handles 2 buckets. NB <= 128.
__global__ __launch_bounds__(64) void bin_scan(const int* __restrict__ gcnt,
                                               int* __restrict__ bstart,
                                               int* __restrict__ cursor, int NB, int E) {
  int t = threadIdx.x;
  int i0 = 2 * t, i1 = 2 * t + 1;
  int v0 = (i0 < NB) ? gcnt[i0] : 0;
  int v1 = (i1 < NB) ? gcnt[i1] : 0;
  int s = v0 + v1, inc = s;
#pragma unroll
  for (int off = 1; off < 64; off <<= 1) {
    int u = __shfl_up(inc, off, 64);
    if (t >= off) inc += u;
  }
  int ex = inc - s;
  if (i0 < NB) { bstart[i0] = ex;      cursor[i0] = ex; }
  if (i1 < NB) { bstart[i1] = ex + v0; cursor[i1] = ex + v0; }
  if (t == 0) bstart[NB] = E;
}

__global__ __launch_bounds__(256) void bin_scatter(const int* __restrict__ src,
                                                   const int* __restrict__ dst,
                                                   int* __restrict__ cursor,
                                                   int* __restrict__ ebuf, int E, int NB) {
  __shared__ int h[MAXNB], loff[MAXNB], gbase[MAXNB];
  __shared__ int sbuf[CHUNK];
  int t = threadIdx.x;
  if (t < MAXNB) h[t] = 0;
  __syncthreads();

  int base = blockIdx.x * CHUNK;
  int myd[CHUNK / 256], mys[CHUNK / 256];
#pragma unroll
  for (int i = 0; i < CHUNK / 256; ++i) {
    int e = base + t + 256 * i;  // coalesced
    if (e < E) {
      myd[i] = dst[e];
      mys[i] = src[e];
      atomicAdd(&h[myd[i] >> BKSH], 1);
    } else myd[i] = -1;
  }
  __syncthreads();

  if (t < 64) {  // wave 0: exclusive scan of h[0..127]
    int i0 = 2 * t, i1 = 2 * t + 1;
    int v0 = h[i0], v1 = h[i1];
    int s = v0 + v1, inc = s;
#pragma unroll
    for (int off = 1; off < 64; off <<= 1) {
      int u = __shfl_up(inc, off, 64);
      if (t >= off) inc += u;
    }
    int ex = inc - s;
    loff[i0] = ex; loff[i1] = ex + v0;
  }
  __syncthreads();

  if (t < NB) {
    if (h[t] > 0) gbase[t] = atomicAdd(&cursor[t], h[t]);  // claim contiguous run
  }
  if (t < MAXNB) h[t] = 0;  // reuse as local cursor
  __syncthreads();

#pragma unroll
  for (int i = 0; i < CHUNK / 256; ++i) {
    if (myd[i] >= 0) {
      int b = myd[i] >> BKSH;
      int p = atomicAdd(&h[b], 1);
      sbuf[loff[b] + p] = mys[i] | ((myd[i] & (BKN - 1)) << 17);  // src < 2^17
    }
  }
  __syncthreads();

  // stream each (block,bucket) run out contiguously
  int w = t >> 6, lane = t & 63;
  for (int b = w; b < NB; b += 4) {
    int c = h[b], lo = loff[b], go = gbase[b];
    for (int j = lane; j < c; j += 64)
      ebuf[go + j] = sbuf[lo + j];
  }
}

// One block per 1024-node bucket: node-sort within the block-private window.
__global__ __launch_bounds__(256) void sb_csr(const int* __restrict__ bstart,
                                              const int* __restrict__ ebuf,
                                              int* __restrict__ col,
                                              int* __restrict__ rowptr,
                                              int N, int E) {
  __shared__ int cnt[BKN], off[BKN];
  __shared__ int wsum[4];
  int b = blockIdx.x, t = threadIdx.x;
  int s = bstart[b], e = bstart[b + 1];
  for (int i = t; i < BKN; i += 256) cnt[i] = 0;
  __syncthreads();
  for (int j = s + t; j < e; j += 256)
    atomicAdd(&cnt[(ebuf[j] >> 17) & (BKN - 1)], 1);
  __syncthreads();

  // block exclusive scan over 1024 (4 per thread)
  int i0 = t * 4;
  int v0 = cnt[i0], v1 = cnt[i0 + 1], v2 = cnt[i0 + 2], v3 = cnt[i0 + 3];
  int tot = v0 + v1 + v2 + v3;
  int lane = t & 63, w = t >> 6;
  int inc = tot;
#pragma unroll
  for (int o = 1; o < 64; o <<= 1) {
    int u = __shfl_up(inc, o, 64);
    if (lane >= o) inc += u;
  }
  if (lane == 63) wsum[w] = inc;
  __syncthreads();
  int wex = 0;
  for (int i = 0; i < w; ++i) wex += wsum[i];
  int ex = wex + inc - tot;
  off[i0] = ex; off[i0 + 1] = ex + v0; off[i0 + 2] = ex + v0 + v1; off[i0 + 3] = ex + v0 + v1 + v2;
  __syncthreads();

  int nbase = b << BKSH;
  for (int i = t; i < BKN; i += 256) {
    int node = nbase + i;
    if (node < N) rowptr[node] = s + off[i];
    cnt[i] = 0;  // reuse as cursor
  }
  __syncthreads();
  for (int j = s + t; j < e; j += 256) {
    int v = ebuf[j];
    int nl = (v >> 17) & (BKN - 1);
    int p = atomicAdd(&cnt[nl], 1);
    col[s + off[nl] + p] = v & 0x1FFFF;  // node-sorted src, block-private lines
  }
  if (b == 0 && t == 0) rowptr[N] = E;
}

// One wave per node. lane = (quarter q, float4 slot d4): quarter q processes
// edges j = s+q, s+q+4, ... with ONE dwordx4 load covering 4 edges per wave-
// iteration (1KB/instr). 2-deep unroll = 8 edges in flight. Cross-quarter
// shuffle reduce at the end; mean folded into the float4 write (quarter 0).
__global__ __launch_bounds__(256) void gcn_gather(const float* __restrict__ x,
                                                  const int* __restrict__ rowptr,
                                                  const int* __restrict__ col,
                                                  float* __restrict__ agg, int N) {
  int gid = blockIdx.x * 256 + threadIdx.x;
  int node = gid >> 6;
  if (node >= N) return;
  int lane = threadIdx.x & 63;
  int q = lane >> 4, d4 = lane & 15;
  int s = rowptr[node], e = rowptr[node + 1];

  float4 a0 = make_float4(0.f, 0.f, 0.f, 0.f);
  float4 a1 = make_float4(0.f, 0.f, 0.f, 0.f);
  int j = s + q;
  for (; j + 4 < e; j += 8) {  // process j and j+4
    int c0 = col[j], c1 = col[j + 4];
    float4 v0 = *(const float4*)&x[(long long)c0 * 64 + d4 * 4];
    float4 v1 = *(const float4*)&x[(long long)c1 * 64 + d4 * 4];
    a0.x += v0.x; a0.y += v0.y; a0.z += v0.z; a0.w += v0.w;
    a1.x += v1.x; a1.y += v1.y; a1.z += v1.z; a1.w += v1.w;
  }
  for (; j < e; j += 4) {
    int c = col[j];
    float4 v = *(const float4*)&x[(long long)c * 64 + d4 * 4];
    a0.x += v.x; a0.y += v.y; a0.z += v.z; a0.w += v.w;
  }
  a0.x += a1.x; a0.y += a1.y; a0.z += a1.z; a0.w += a1.w;

  // reduce across the 4 quarters (lanes l, l^16, l^32, l^48)
#pragma unroll
  for (int m = 16; m <= 32; m <<= 1) {
    a0.x += __shfl_xor(a0.x, m, 64);
    a0.y += __shfl_xor(a0.y, m, 64);
    a0.z += __shfl_xor(a0.z, m, 64);
    a0.w += __shfl_xor(a0.w, m, 64);
  }

  if (q == 0) {
    float cnt = (float)(e - s);
    float inv = 1.0f / fmaxf(cnt, 1.0f);
    a0.x *= inv; a0.y *= inv; a0.z *= inv; a0.w *= inv;
    *(float4*)&agg[(long long)node * 64 + d4 * 4] = a0;  // 16 lanes x 16B = 256B
  }
}

static __device__ inline void fma4(float4& a, float s, const float4& w) {
  a.x = fmaf(s, w.x, a.x);
  a.y = fmaf(s, w.y, a.y);
  a.z = fmaf(s, w.z, a.z);
  a.w = fmaf(s, w.w, a.w);
}

// 64-node tile per block; thread (tn,to) computes nodes 4tn..4tn+3 x outs 4to..4to+3.
// All LDS rows stride LP=65: staging writes hit bank (lane+c)%32 -> conflict-free;
// k-loop reads are broadcast or 2-way (free). agg_out is d_out.
__global__ __launch_bounds__(256) void gcn_gemm(const float* __restrict__ x,
                                                float* __restrict__ agg_out,
                                                const float* __restrict__ Wself,
                                                const float* __restrict__ bself,
                                                const float* __restrict__ Wneigh,
                                                int N) {
  __shared__ __align__(16) float sWs[64 * LP];  // sWs[k*LP+o] = Wself[o][k]
  __shared__ __align__(16) float sWn[64 * LP];
  __shared__ __align__(16) float xT[64 * LP];   // xT[k*LP+n] = x[node][k]
  __shared__ __align__(16) float aT[64 * LP];
  int tid = threadIdx.x;
  int gBase = blockIdx.x * 64;

  for (int i = tid; i < 4096; i += 256) {
    int o = i >> 6, k = i & 63;   // k = lane -> LDS bank (k+o)%32, conflict-free
    sWs[k * LP + o] = Wself[i];
    sWn[k * LP + o] = Wneigh[i];
  }
  for (int i = tid; i < 4096; i += 256) {
    int n = i >> 6, k = i & 63;   // global: coalesced row; LDS: conflict-free
    int node = gBase + n;
    float xv = 0.f, av = 0.f;
    if (node < N) {
      xv = x[(long long)node * 64 + k];
      av = agg_out[(long long)node * 64 + k];
    }
    xT[k * LP + n] = xv;
    aT[k * LP + n] = av;
  }
  __syncthreads();

  int to = tid & 15, tn = tid >> 4;
  float4 acc[4];
#pragma unroll
  for (int i = 0; i < 4; ++i) acc[i] = make_float4(0.f, 0.f, 0.f, 0.f);

#pragma unroll 8
  for (int k = 0; k < 64; ++k) {
    float4 xa = *(const float4*)&xT[k * LP + 4 * tn];
    float4 aa = *(const float4*)&aT[k * LP + 4 * tn];
    float4 ws = *(const float4*)&sWs[k * LP + 4 * to];
    float4 wn = *(const float4*)&sWn[k * LP + 4 * to];
    fma4(acc[0], xa.x, ws); fma4(acc[0], aa.x, wn);
    fma4(acc[1], xa.y, ws); fma4(acc[1], aa.y, wn);
    fma4(acc[2], xa.z, ws); fma4(acc[2], aa.z, wn);
    fma4(acc[3], xa.w, ws); fma4(acc[3], aa.w, wn);
  }

  float4 bv = *(const float4*)&bself[4 * to];
#pragma unroll
  for (int i = 0; i < 4; ++i) {
    int node = gBase + 4 * tn + i;
    if (node < N) {
      float4 v = acc[i];
      v.x = fmaxf(v.x + bv.x, 0.f);
      v.y = fmaxf(v.y + bv.y, 0.f);
      v.z = fmaxf(v.z + bv.z, 0.f);
      v.w = fmaxf(v.w + bv.w, 0.f);
      *(float4*)&agg_out[(long long)node * 64 + 4 * to] = v;
    }
  }
}

extern "C" void kernel_launch(void* const* d_in, const int* in_sizes, int n_in,
                              void* d_out, int out_size, void* d_ws, size_t ws_size,
                              hipStream_t stream) {
  const float* x      = (const float*)d_in[0];
  const int*   eidx   = (const int*)d_in[1];
  const float* Wself  = (const float*)d_in[2];
  const float* bself  = (const float*)d_in[3];
  const float* Wneigh = (const float*)d_in[4];
  float* out = (float*)d_out;

  const int N = in_sizes[0] / 64;
  const int E = in_sizes[1] / 2;
  const int* src = eidx;      // edge_index row 0
  const int* dst = eidx + E;  // edge_index row 1
  const int NB = (N + BKN - 1) / BKN;  // 98 buckets of 1024 nodes

  // ws layout (ints): gcnt[128] | cursor[128] | bstart[128] | rowptr[N+1]
  //                   | ebuf[E] | col[E]
  int* gcnt   = (int*)d_ws;
  int* cursor = gcnt + MAXNB;
  int* bstart = cursor + MAXNB;
  int* rowptr = bstart + MAXNB;
  int* ebuf   = rowptr + N + 1;
  int* col    = ebuf + E;

  hipMemsetAsync(gcnt, 0, MAXNB * sizeof(int), stream);

  int cb = (E + CHUNK - 1) / CHUNK;  // 306 binning blocks
  bin_hist<<<cb, 256, 0, stream>>>(dst, gcnt, E, NB);
  bin_scan<<<1, 64, 0, stream>>>(gcnt, bstart, cursor, NB, E);
  bin_scatter<<<cb, 256, 0, stream>>>(src, dst, cursor, ebuf, E, NB);
  sb_csr<<<NB, 256, 0, stream>>>(bstart, ebuf, col, rowptr, N, E);
  gcn_gather<<<(N * 64 + 255) / 256, 256, 0, stream>>>(x, rowptr, col, out, N);
  gcn_gemm<<<(N + 63) / 64, 256, 0, stream>>>(x, out, Wself, bself, Wneigh, N);
}

// Round 9
// 219.273 us; speedup vs baseline: 3.6086x; 1.1041x over previous
//
#include <hip/hip_runtime.h>

// GCN layer: out = relu(x @ W_self^T + b_self + segment_mean(x[src], dst) @ W_neigh^T)
// N = 100000 nodes, D = 64, E = 1.25M edges.
//
// Pipeline:
//   bin_hist    : per-block LDS hist of 4096-edge chunk (int4 loads) -> 1 global
//                 atomic per (block,bucket). Buckets = 1024 consecutive dst nodes.
//   bin_scan    : one-wave exclusive scan of the 98 bucket counts.
//   bin_scatter : LDS-staged radix scatter; every ebuf line written by ONE block.
//   sb_csr      : one block per 1024-node bucket -> exact CSR, block-private lines.
//   gcn_gather  : one wave per node, 16 lanes x float4 per row -> 4 edges per VMEM
//                 instruction (1KB), 2-deep unroll, shuffle cross-quarter reduce.
//   gcn_gemm    : bf16 MFMA (16x16x32), ZERO LDS — all fragments straight from
//                 global (W is L1/L2-resident), both matmuls chained into one
//                 accumulator, bias+relu fused. agg lives in d_out.

#define BKSH 10               // log2(nodes per bucket)
#define BKN 1024              // nodes per bucket
#define CHUNK 4096            // edges per binning block
#define MAXNB 128             // >= NB = ceil(N / BKN) = 98

typedef __attribute__((ext_vector_type(8))) short short8;
typedef __attribute__((ext_vector_type(4))) float floatx4;

__global__ __launch_bounds__(256) void bin_hist(const int* __restrict__ dst,
                                                int* __restrict__ gcnt, int E, int NB) {
  __shared__ int h[MAXNB];
  int t = threadIdx.x;
  if (t < MAXNB) h[t] = 0;
  __syncthreads();
  int base = blockIdx.x * CHUNK;
  if (base + CHUNK <= E) {  // full chunk: int4 loads
    const int4* d4 = (const int4*)(dst + base);
#pragma unroll
    for (int i = 0; i < 4; ++i) {
      int4 v = d4[t + 256 * i];
      atomicAdd(&h[v.x >> BKSH], 1);
      atomicAdd(&h[v.y >> BKSH], 1);
      atomicAdd(&h[v.z >> BKSH], 1);
      atomicAdd(&h[v.w >> BKSH], 1);
    }
  } else {
    for (int i = t; i < CHUNK; i += 256) {
      int e = base + i;
      if (e < E) atomicAdd(&h[dst[e] >> BKSH], 1);
    }
  }
  __syncthreads();
  if (t < NB && h[t]) atomicAdd(&gcnt[t], h[t]);
}

// One wave; thread handles 2 buckets. NB <= 128.
__global__ __launch_bounds__(64) void bin_scan(const int* __restrict__ gcnt,
                                               int* __restrict__ bstart,
                                               int* __restrict__ cursor, int NB, int E) {
  int t = threadIdx.x;
  int i0 = 2 * t, i1 = 2 * t + 1;
  int v0 = (i0 < NB) ? gcnt[i0] : 0;
  int v1 = (i1 < NB) ? gcnt[i1] : 0;
  int s = v0 + v1, inc = s;
#pragma unroll
  for (int off = 1; off < 64; off <<= 1) {
    int u = __shfl_up(inc, off, 64);
    if (t >= off) inc += u;
  }
  int ex = inc - s;
  if (i0 < NB) { bstart[i0] = ex;      cursor[i0] = ex; }
  if (i1 < NB) { bstart[i1] = ex + v0; cursor[i1] = ex + v0; }
  if (t == 0) bstart[NB] = E;
}

__global__ __launch_bounds__(256) void bin_scatter(const int* __restrict__ src,
                                                   const int* __restrict__ dst,
                                                   int* __restrict__ cursor,
                                                   int* __restrict__ ebuf, int E, int NB) {
  __shared__ int h[MAXNB], loff[MAXNB], gbase[MAXNB];
  __shared__ int sbuf[CHUNK];
  int t = threadIdx.x;
  if (t < MAXNB) h[t] = 0;
  __syncthreads();

  int base = blockIdx.x * CHUNK;
  int myd[CHUNK / 256], mys[CHUNK / 256];
#pragma unroll
  for (int i = 0; i < CHUNK / 256; ++i) {
    int e = base + t + 256 * i;  // coalesced
    if (e < E) {
      myd[i] = dst[e];
      mys[i] = src[e];
      atomicAdd(&h[myd[i] >> BKSH], 1);
    } else myd[i] = -1;
  }
  __syncthreads();

  if (t < 64) {  // wave 0: exclusive scan of h[0..127]
    int i0 = 2 * t, i1 = 2 * t + 1;
    int v0 = h[i0], v1 = h[i1];
    int s = v0 + v1, inc = s;
#pragma unroll
    for (int off = 1; off < 64; off <<= 1) {
      int u = __shfl_up(inc, off, 64);
      if (t >= off) inc += u;
    }
    int ex = inc - s;
    loff[i0] = ex; loff[i1] = ex + v0;
  }
  __syncthreads();

  if (t < NB) {
    if (h[t] > 0) gbase[t] = atomicAdd(&cursor[t], h[t]);  // claim contiguous run
  }
  if (t < MAXNB) h[t] = 0;  // reuse as local cursor
  __syncthreads();

#pragma unroll
  for (int i = 0; i < CHUNK / 256; ++i) {
    if (myd[i] >= 0) {
      int b = myd[i] >> BKSH;
      int p = atomicAdd(&h[b], 1);
      sbuf[loff[b] + p] = mys[i] | ((myd[i] & (BKN - 1)) << 17);  // src < 2^17
    }
  }
  __syncthreads();

  // stream each (block,bucket) run out contiguously
  int w = t >> 6, lane = t & 63;
  for (int b = w; b < NB; b += 4) {
    int c = h[b], lo = loff[b], go = gbase[b];
    for (int j = lane; j < c; j += 64)
      ebuf[go + j] = sbuf[lo + j];
  }
}

// One block per 1024-node bucket: node-sort within the block-private window.
__global__ __launch_bounds__(256) void sb_csr(const int* __restrict__ bstart,
                                              const int* __restrict__ ebuf,
                                              int* __restrict__ col,
                                              int* __restrict__ rowptr,
                                              int N, int E) {
  __shared__ int cnt[BKN], off[BKN];
  __shared__ int wsum[4];
  int b = blockIdx.x, t = threadIdx.x;
  int s = bstart[b], e = bstart[b + 1];
  for (int i = t; i < BKN; i += 256) cnt[i] = 0;
  __syncthreads();
  for (int j = s + t; j < e; j += 256)
    atomicAdd(&cnt[(ebuf[j] >> 17) & (BKN - 1)], 1);
  __syncthreads();

  // block exclusive scan over 1024 (4 per thread)
  int i0 = t * 4;
  int v0 = cnt[i0], v1 = cnt[i0 + 1], v2 = cnt[i0 + 2], v3 = cnt[i0 + 3];
  int tot = v0 + v1 + v2 + v3;
  int lane = t & 63, w = t >> 6;
  int inc = tot;
#pragma unroll
  for (int o = 1; o < 64; o <<= 1) {
    int u = __shfl_up(inc, o, 64);
    if (lane >= o) inc += u;
  }
  if (lane == 63) wsum[w] = inc;
  __syncthreads();
  int wex = 0;
  for (int i = 0; i < w; ++i) wex += wsum[i];
  int ex = wex + inc - tot;
  off[i0] = ex; off[i0 + 1] = ex + v0; off[i0 + 2] = ex + v0 + v1; off[i0 + 3] = ex + v0 + v1 + v2;
  __syncthreads();

  int nbase = b << BKSH;
  for (int i = t; i < BKN; i += 256) {
    int node = nbase + i;
    if (node < N) rowptr[node] = s + off[i];
    cnt[i] = 0;  // reuse as cursor
  }
  __syncthreads();
  for (int j = s + t; j < e; j += 256) {
    int v = ebuf[j];
    int nl = (v >> 17) & (BKN - 1);
    int p = atomicAdd(&cnt[nl], 1);
    col[s + off[nl] + p] = v & 0x1FFFF;  // node-sorted src, block-private lines
  }
  if (b == 0 && t == 0) rowptr[N] = E;
}

// One wave per node. Quarter q processes edges j = s+q, s+q+4, ... with ONE
// dwordx4 load covering 4 edges per wave-iteration (1KB/instr). 2-deep unroll.
__global__ __launch_bounds__(256) void gcn_gather(const float* __restrict__ x,
                                                  const int* __restrict__ rowptr,
                                                  const int* __restrict__ col,
                                                  float* __restrict__ agg, int N) {
  int gid = blockIdx.x * 256 + threadIdx.x;
  int node = gid >> 6;
  if (node >= N) return;
  int lane = threadIdx.x & 63;
  int q = lane >> 4, d4 = lane & 15;
  int s = rowptr[node], e = rowptr[node + 1];

  float4 a0 = make_float4(0.f, 0.f, 0.f, 0.f);
  float4 a1 = make_float4(0.f, 0.f, 0.f, 0.f);
  int j = s + q;
  for (; j + 4 < e; j += 8) {  // process j and j+4
    int c0 = col[j], c1 = col[j + 4];
    float4 v0 = *(const float4*)&x[(long long)c0 * 64 + d4 * 4];
    float4 v1 = *(const float4*)&x[(long long)c1 * 64 + d4 * 4];
    a0.x += v0.x; a0.y += v0.y; a0.z += v0.z; a0.w += v0.w;
    a1.x += v1.x; a1.y += v1.y; a1.z += v1.z; a1.w += v1.w;
  }
  for (; j < e; j += 4) {
    int c = col[j];
    float4 v = *(const float4*)&x[(long long)c * 64 + d4 * 4];
    a0.x += v.x; a0.y += v.y; a0.z += v.z; a0.w += v.w;
  }
  a0.x += a1.x; a0.y += a1.y; a0.z += a1.z; a0.w += a1.w;

#pragma unroll
  for (int m = 16; m <= 32; m <<= 1) {
    a0.x += __shfl_xor(a0.x, m, 64);
    a0.y += __shfl_xor(a0.y, m, 64);
    a0.z += __shfl_xor(a0.z, m, 64);
    a0.w += __shfl_xor(a0.w, m, 64);
  }

  if (q == 0) {
    float cnt = (float)(e - s);
    float inv = 1.0f / fmaxf(cnt, 1.0f);
    a0.x *= inv; a0.y *= inv; a0.z *= inv; a0.w *= inv;
    *(float4*)&agg[(long long)node * 64 + d4 * 4] = a0;  // 16 lanes x 16B = 256B
  }
}

// fp32 -> bf16 round-to-nearest-even, branch-free bit arithmetic.
static __device__ inline unsigned short f2bf(float f) {
  union { float f; unsigned int u; } v;
  v.f = f;
  unsigned int r = v.u + 0x7FFFu + ((v.u >> 16) & 1u);
  return (unsigned short)(r >> 16);
}

// Pack 8 consecutive fp32 into a bf16x8 MFMA fragment.
static __device__ inline short8 pack8(float4 a, float4 b) {
  short8 s;
  s[0] = (short)f2bf(a.x); s[1] = (short)f2bf(a.y);
  s[2] = (short)f2bf(a.z); s[3] = (short)f2bf(a.w);
  s[4] = (short)f2bf(b.x); s[5] = (short)f2bf(b.y);
  s[6] = (short)f2bf(b.z); s[7] = (short)f2bf(b.w);
  return s;
}

// bf16 MFMA GEMM epilogue, zero LDS. Block = 4 waves; wave w owns nodes
// [blk*64 + w*16, +16). A-frag: X[m=lane&15][k=quad*8+j] straight from global
// (2 float4/lane per 32-k step); same for AGG (= d_out, read before overwrite,
// rows wave-private). B-frag: W[o=lane&15][k=quad*8+j] — W is 32KB, L1/L2-hot.
// Both matmuls chain into ONE accumulator: D = Ax*Ws^T + Aagg*Wn^T.
// C/D layout: col=lane&15, row=quad*4+reg (HW-verified m89/m91).
__global__ __launch_bounds__(256) void gcn_gemm(const float* __restrict__ x,
                                                float* __restrict__ agg_out,
                                                const float* __restrict__ Wself,
                                                const float* __restrict__ bself,
                                                const float* __restrict__ Wneigh,
                                                int N) {
  int lane = threadIdx.x & 63;
  int w = threadIdx.x >> 6;
  int tb = blockIdx.x * 64 + w * 16;   // this wave's 16-node tile
  int m = lane & 15, q = lane >> 4;

  // A-fragments for X and AGG (2 k-steps of 32)
  long long rowA = (long long)min(tb + m, N - 1) * 64;
  short8 ax[2], aa[2];
#pragma unroll
  for (int ks = 0; ks < 2; ++ks) {
    const float* px = &x[rowA + ks * 32 + q * 8];
    ax[ks] = pack8(*(const float4*)px, *(const float4*)(px + 4));
    const float* pa = &agg_out[rowA + ks * 32 + q * 8];
    aa[ks] = pack8(*(const float4*)pa, *(const float4*)(pa + 4));
  }

#pragma unroll
  for (int nt = 0; nt < 4; ++nt) {
    int ob = nt * 16;                       // output-column tile base
    long long rowB = (long long)(ob + m) * 64;
    floatx4 acc = {0.f, 0.f, 0.f, 0.f};
#pragma unroll
    for (int ks = 0; ks < 2; ++ks) {
      const float* pw = &Wself[rowB + ks * 32 + q * 8];
      short8 bw = pack8(*(const float4*)pw, *(const float4*)(pw + 4));
      acc = __builtin_amdgcn_mfma_f32_16x16x32_bf16(ax[ks], bw, acc, 0, 0, 0);
      const float* pn = &Wneigh[rowB + ks * 32 + q * 8];
      short8 bn = pack8(*(const float4*)pn, *(const float4*)(pn + 4));
      acc = __builtin_amdgcn_mfma_f32_16x16x32_bf16(aa[ks], bn, acc, 0, 0, 0);
    }
    float bias = bself[ob + m];             // col = lane&15 = m
#pragma unroll
    for (int r = 0; r < 4; ++r) {
      int node = tb + q * 4 + r;            // row = quad*4 + reg
      if (node < N) {
        float v = acc[r] + bias;
        agg_out[(long long)node * 64 + ob + m] = fmaxf(v, 0.f);
      }
    }
  }
}

extern "C" void kernel_launch(void* const* d_in, const int* in_sizes, int n_in,
                              void* d_out, int out_size, void* d_ws, size_t ws_size,
                              hipStream_t stream) {
  const float* x      = (const float*)d_in[0];
  const int*   eidx   = (const int*)d_in[1];
  const float* Wself  = (const float*)d_in[2];
  const float* bself  = (const float*)d_in[3];
  const float* Wneigh = (const float*)d_in[4];
  float* out = (float*)d_out;

  const int N = in_sizes[0] / 64;
  const int E = in_sizes[1] / 2;
  const int* src = eidx;      // edge_index row 0
  const int* dst = eidx + E;  // edge_index row 1
  const int NB = (N + BKN - 1) / BKN;  // 98 buckets of 1024 nodes

  // ws layout (ints): gcnt[128] | cursor[128] | bstart[128] | rowptr[N+1]
  //                   | ebuf[E] | col[E]
  int* gcnt   = (int*)d_ws;
  int* cursor = gcnt + MAXNB;
  int* bstart = cursor + MAXNB;
  int* rowptr = bstart + MAXNB;
  int* ebuf   = rowptr + N + 1;
  int* col    = ebuf + E;

  (void)hipMemsetAsync(gcnt, 0, MAXNB * sizeof(int), stream);

  int cb = (E + CHUNK - 1) / CHUNK;  // 306 binning blocks
  bin_hist<<<cb, 256, 0, stream>>>(dst, gcnt, E, NB);
  bin_scan<<<1, 64, 0, stream>>>(gcnt, bstart, cursor, NB, E);
  bin_scatter<<<cb, 256, 0, stream>>>(src, dst, cursor, ebuf, E, NB);
  sb_csr<<<NB, 256, 0, stream>>>(bstart, ebuf, col, rowptr, N, E);
  gcn_gather<<<(N * 64 + 255) / 256, 256, 0, stream>>>(x, rowptr, col, out, N);
  gcn_gemm<<<(N + 63) / 64, 256, 0, stream>>>(x, out, Wself, bself, Wneigh, N);
}